// Round 9
// baseline (458.784 us; speedup 1.0000x reference)
//
#include <hip/hip_runtime.h>

typedef unsigned short u16;
typedef unsigned int u32;
typedef short bf16x8 __attribute__((ext_vector_type(8)));
typedef float f32x4 __attribute__((ext_vector_type(4)));
typedef unsigned short u16x8 __attribute__((ext_vector_type(8)));
typedef unsigned short u16x4 __attribute__((ext_vector_type(4)));

#define DEVFN static __device__ __forceinline__

DEVFN u16 f2b(float f) {
    u32 u = __builtin_bit_cast(u32, f);
    u += 0x7FFFu + ((u >> 16) & 1u);
    return (u16)(u >> 16);
}
DEVFN float b2f(u16 h) {
    u32 u = ((u32)h) << 16;
    return __builtin_bit_cast(float, u);
}

typedef const __attribute__((address_space(1))) unsigned int glb_u32;
typedef __attribute__((address_space(3))) unsigned int lds_u32;
DEVFN void gload_lds16(const u16* g, u16* l) {
    __builtin_amdgcn_global_load_lds((glb_u32*)g, (lds_u32*)l, 16, 0, 0);
}

// ---------------------------------------------------------------- prep ----
__global__ void k_prep(const float* __restrict__ qkvw, const float* __restrict__ pjw,
                       u16* __restrict__ qkvwb, u16* __restrict__ pjwb) {
    int id = blockIdx.x * 256 + threadIdx.x;
    if (id < 196608) qkvwb[id] = f2b(qkvw[id]);
    if (id < 65536)  pjwb[id]  = f2b(pjw[id]);
}

__global__ void k_cpb(const float* __restrict__ w1, const float* __restrict__ b1,
                      const float* __restrict__ w2, float* __restrict__ bt) {
    int p = threadIdx.x;
    if (p >= 225) return;
    int d0 = p / 15, d1 = p % 15;
    float v0 = (float)(d0 - 7) * (8.0f / 7.0f);
    float v1 = (float)(d1 - 7) * (8.0f / 7.0f);
    float t0 = copysignf(log2f(fabsf(v0) + 1.0f) * (1.0f / 3.0f), v0);
    float t1 = copysignf(log2f(fabsf(v1) + 1.0f) * (1.0f / 3.0f), v1);
    float s[8] = {0.f, 0.f, 0.f, 0.f, 0.f, 0.f, 0.f, 0.f};
    for (int d = 0; d < 256; ++d) {
        float h = t0 * w1[2 * d] + t1 * w1[2 * d + 1] + b1[d];
        h = fmaxf(h, 0.0f);
        #pragma unroll
        for (int hh = 0; hh < 8; ++hh) s[hh] += h * w2[hh * 256 + d];
    }
    #pragma unroll
    for (int hh = 0; hh < 8; ++hh) bt[p * 8 + hh] = s[hh];
}

// TRANSPOSED bias table: biasT[h][k][q]
__global__ void k_bias(const float* __restrict__ bt, float* __restrict__ biasT) {
    int id = blockIdx.x * 256 + threadIdx.x;  // id = k*64 + q
    int kq = id >> 6, q = id & 63;
    int d0 = (q >> 3) - (kq >> 3) + 7;
    int d1 = (q & 7) - (kq & 7) + 7;
    int p = d0 * 15 + d1;
    #pragma unroll
    for (int h = 0; h < 8; ++h)
        biasT[h * 4096 + id] = 16.0f / (1.0f + expf(-bt[p * 8 + h]));
}

// ---------------------------------------------------------------- xcvt ----
// x fp32 NCHW -> bf16, written in k_qkv's swizzled LDS-tile order:
// xt[rowblk][chunk][tok*64 + ((g ^ swz(tok))<<3) + j] = x[c*64+g*8+j][rowblk][tok]
__global__ __launch_bounds__(256) void k_xcvt(const float* __restrict__ x,
                                              u16* __restrict__ xt) {
    const int bid = blockIdx.x;              // 4096 = 1024 rowblk * 4 chunk
    const int c = bid & 3, rowblk = bid >> 2;
    const int tid = threadIdx.x;
    const int g = tid >> 5;                  // 8-ch group 0..7
    const int tok0 = (tid & 31) * 4;
    const float* src = x + ((size_t)(rowblk >> 7) * 256 + c * 64 + g * 8) * 16384
                         + (rowblk & 127) * 128 + tok0;
    float4 v[8];
    #pragma unroll
    for (int j = 0; j < 8; ++j)
        v[j] = *(const float4*)(src + (size_t)j * 16384);
    u16x8 o0, o1, o2, o3;
    #pragma unroll
    for (int j = 0; j < 8; ++j) {
        o0[j] = f2b(v[j].x);
        o1[j] = f2b(v[j].y);
        o2[j] = f2b(v[j].z);
        o3[j] = f2b(v[j].w);
    }
    const int tq = tok0 >> 2;                // (tok0+i)>>2 constant for i<4
    const int s0 = g ^ ((tq ^ (tok0 + 0)) & 7);
    const int s1 = g ^ ((tq ^ (tok0 + 1)) & 7);
    const int s2 = g ^ ((tq ^ (tok0 + 2)) & 7);
    const int s3 = g ^ ((tq ^ (tok0 + 3)) & 7);
    u16* dst = xt + ((size_t)rowblk * 4 + c) * 8192;
    *(u16x8*)&dst[(tok0 + 0) * 64 + (s0 << 3)] = o0;
    *(u16x8*)&dst[(tok0 + 1) * 64 + (s1 << 3)] = o1;
    *(u16x8*)&dst[(tok0 + 2) * 64 + (s2 << 3)] = o2;
    *(u16x8*)&dst[(tok0 + 3) * 64 + (s3 << 3)] = o3;
}

// ---------------------------------------------------------------- qkv -----
// Staging via global_load_lds from pre-swizzled xt: zero staging VGPRs/VALU.
// GEMM + epilogue verbatim from R8 (D[och][tok], vectorized u16x4 stores).
__global__ __launch_bounds__(256, 4) void k_qkv(
    const u16* __restrict__ xt, const u16* __restrict__ qkvw,
    const float* __restrict__ qkvb,
    u16* __restrict__ gq, u16* __restrict__ gk, u16* __restrict__ wv_g) {
    __shared__ __align__(16) u16 Xs[2][8192];  // [128 tok][64 ch] swizzled

    const int bid = blockIdx.x;                 // 6144 = 8 xcd * 128 rowblk * 6 ny
    const int xcd = bid & 7;
    const int idx = bid >> 3;
    const int ny = idx % 6;
    const int rowblk = xcd * 128 + idx / 6;
    const int b = rowblk >> 7, row = rowblk & 127;
    const int which = ny >> 1, half = ny & 1;

    const int tid = threadIdx.x;
    const int wave = tid >> 6, l = tid & 63, col = l & 15, quad = l >> 4;
    const int th = wave >> 1;
    const int oq = wave & 1;
    const int obase = half * 128 + oq * 64;

    int orow[4];
    #pragma unroll
    for (int nt = 0; nt < 4; ++nt) {
        const int oo = obase + nt * 16 + col;
        orow[nt] = (oo >> 5) * 96 + which * 32 + (oo & 31);
    }

    f32x4 acc[4][4];                            // [nt(och)][mt(tok)]
    #pragma unroll
    for (int i = 0; i < 4; ++i)
        #pragma unroll
        for (int j = 0; j < 4; ++j) acc[i][j] = f32x4{0.f, 0.f, 0.f, 0.f};

    const u16* xtb = xt + (size_t)rowblk * 32768;

    auto stage = [&](int c, int buf) {
        const u16* src = xtb + c * 8192 + wave * 2048 + l * 8;
        u16* dst = &Xs[buf][wave * 2048];
        #pragma unroll
        for (int i = 0; i < 4; ++i)
            gload_lds16(src + i * 512, dst + i * 512);
    };
    auto gemm = [&](int c, int buf) {
        #pragma unroll
        for (int kk = 0; kk < 2; ++kk) {
            const int cb = c * 64 + kk * 32 + quad * 8;
            const int lchunk = kk * 4 + quad;
            bf16x8 bw[4];
            #pragma unroll
            for (int nt = 0; nt < 4; ++nt)
                bw[nt] = *(const bf16x8*)&qkvw[(size_t)orow[nt] * 256 + cb];
            bf16x8 af[4];
            #pragma unroll
            for (int mt = 0; mt < 4; ++mt) {
                const int tok = th * 64 + mt * 16 + col;
                const int slot = lchunk ^ (((tok >> 2) ^ tok) & 7);
                af[mt] = *(const bf16x8*)&Xs[buf][tok * 64 + (slot << 3)];
            }
            #pragma unroll
            for (int nt = 0; nt < 4; ++nt)
                #pragma unroll
                for (int mt = 0; mt < 4; ++mt)
                    acc[nt][mt] = __builtin_amdgcn_mfma_f32_16x16x32_bf16(
                        bw[nt], af[mt], acc[nt][mt], 0, 0, 0);
        }
    };

    stage(0, 0);
    __syncthreads();
    #pragma unroll
    for (int c = 0; c < 4; ++c) {
        if (c < 3) stage(c + 1, (c + 1) & 1);   // prefetch next chunk (T14)
        gemm(c, c & 1);
        __syncthreads();                         // drains vmcnt (m97 pattern)
    }

    // epilogue: D[och][tok] (R8 verbatim)
    const int hA = obase >> 5;
    f32x4 bqv[4];
    #pragma unroll
    for (int nt = 0; nt < 4; ++nt) {
        const int oo = obase + nt * 16 + quad * 4;
        bqv[nt] = *(const f32x4*)&qkvb[(oo >> 5) * 96 + which * 32 + (oo & 31)];
    }
    #pragma unroll
    for (int mt = 0; mt < 4; ++mt) {
        const int tok = th * 64 + mt * 16 + col;
        const int win = b * 256 + (row >> 3) * 16 + (tok >> 3);
        const int tk = (row & 7) * 8 + (tok & 7);
        float v[4][4];
        #pragma unroll
        for (int nt = 0; nt < 4; ++nt)
            #pragma unroll
            for (int r = 0; r < 4; ++r)
                v[nt][r] = acc[nt][mt][r] + bqv[nt][r];
        if (which < 2) {
            float sA = 0.f, sB = 0.f;
            #pragma unroll
            for (int r = 0; r < 4; ++r) {
                sA += v[0][r] * v[0][r] + v[1][r] * v[1][r];
                sB += v[2][r] * v[2][r] + v[3][r] * v[3][r];
            }
            sA += __shfl_xor(sA, 16, 64);
            sA += __shfl_xor(sA, 32, 64);
            sB += __shfl_xor(sB, 16, 64);
            sB += __shfl_xor(sB, 32, 64);
            const float iA = 1.0f / fmaxf(sqrtf(sA), 1e-12f);
            const float iB = 1.0f / fmaxf(sqrtf(sB), 1e-12f);
            #pragma unroll
            for (int r = 0; r < 4; ++r) {
                v[0][r] *= iA; v[1][r] *= iA;
                v[2][r] *= iB; v[3][r] *= iB;
            }
        }
        #pragma unroll
        for (int nt = 0; nt < 4; ++nt) {
            u16x4 ov;
            #pragma unroll
            for (int r = 0; r < 4; ++r) ov[r] = f2b(v[nt][r]);
            if (which == 2) {
                *(u16x4*)&wv_g[((size_t)win * 64 + tk) * 256 + obase + nt * 16 + quad * 4] = ov;
            } else {
                u16* G = (which == 0) ? gq : gk;
                const int h = hA + (nt >> 1);
                const int d = (nt & 1) * 16 + quad * 4;
                *(u16x4*)&G[((size_t)(win * 8 + h) * 64 + tk) * 32 + d] = ov;
            }
        }
    }
}

// ---------------------------------------------------------------- attn ----
// R8 verbatim: S^T layout, in-register softmax, P^T packed from regs.
__global__ __launch_bounds__(256, 3) void k_attn3(
    const u16* __restrict__ gq, const u16* __restrict__ gk,
    const u16* __restrict__ wv_g,
    const float* __restrict__ lsc, const float* __restrict__ biasT,
    u16* __restrict__ wout_g) {
    __shared__ __align__(16) u16 scr[4][2048];  // per wave: v_t only

    const int tid = threadIdx.x;
    const int wave = tid >> 6, l = tid & 63, col = l & 15, quad = l >> 4;
    const int job = blockIdx.x * 4 + wave;
    const int h = job >> 11, win = job & 2047;
    u16* const v_t = scr[wave];  // [32 d][64 pi-slot] swz(d&7)

    #pragma unroll
    for (int it = 0; it < 4; ++it) {
        const int idx = it * 64 + l;
        const int tok = idx & 63, dblk = idx >> 6;
        const u16x8 vv = *(const u16x8*)&wv_g[((size_t)win * 64 + tok) * 256 + h * 32 + dblk * 8];
        const int g = (tok >> 5) * 4 + ((tok >> 2) & 3);
        const int jj = ((tok >> 4) & 1) * 4 + (tok & 3);
        #pragma unroll
        for (int j = 0; j < 8; ++j) {
            const int d = dblk * 8 + j;
            v_t[d * 64 + (((g ^ (d & 7)) << 3) | jj)] = vv[j];
        }
    }

    const u16* const qbp = gq + (size_t)(win * 8 + h) * 2048;
    const u16* const kbp = gk + (size_t)(win * 8 + h) * 2048;
    bf16x8 ak[4], bq[4];
    #pragma unroll
    for (int mt = 0; mt < 4; ++mt)
        ak[mt] = *(const bf16x8*)&kbp[(mt * 16 + col) * 32 + quad * 8];
    #pragma unroll
    for (int nt = 0; nt < 4; ++nt)
        bq[nt] = *(const bf16x8*)&qbp[(nt * 16 + col) * 32 + quad * 8];

    const f32x4 zero4 = {0.f, 0.f, 0.f, 0.f};
    f32x4 sacc[4][4];
    #pragma unroll
    for (int mt = 0; mt < 4; ++mt)
        #pragma unroll
        for (int nt = 0; nt < 4; ++nt)
            sacc[mt][nt] = __builtin_amdgcn_mfma_f32_16x16x32_bf16(ak[mt], bq[nt], zero4, 0, 0, 0);

    const float ls = expf(fminf(lsc[h], 4.6051701859880914f));
    const float* bT = biasT + h * 4096;
    #pragma unroll
    for (int nt = 0; nt < 4; ++nt) {
        const int q = nt * 16 + col;
        float v[4][4];
        float mx = -1e30f;
        #pragma unroll
        for (int mt = 0; mt < 4; ++mt)
            #pragma unroll
            for (int r = 0; r < 4; ++r) {
                v[mt][r] = sacc[mt][nt][r] * ls + bT[(mt * 16 + quad * 4 + r) * 64 + q];
                mx = fmaxf(mx, v[mt][r]);
            }
        mx = fmaxf(mx, __shfl_xor(mx, 16, 64));
        mx = fmaxf(mx, __shfl_xor(mx, 32, 64));
        float s = 0.f;
        #pragma unroll
        for (int mt = 0; mt < 4; ++mt)
            #pragma unroll
            for (int r = 0; r < 4; ++r) {
                v[mt][r] = expf(v[mt][r] - mx);
                s += v[mt][r];
            }
        s += __shfl_xor(s, 16, 64);
        s += __shfl_xor(s, 32, 64);
        const float inv = 1.0f / s;
        #pragma unroll
        for (int mt = 0; mt < 4; ++mt)
            #pragma unroll
            for (int r = 0; r < 4; ++r)
                sacc[mt][nt][r] = v[mt][r] * inv;
    }

    f32x4 oacc[2][4];
    #pragma unroll
    for (int i = 0; i < 2; ++i)
        #pragma unroll
        for (int j = 0; j < 4; ++j) oacc[i][j] = zero4;
    #pragma unroll
    for (int kk = 0; kk < 2; ++kk) {
        bf16x8 av[2];
        #pragma unroll
        for (int dt = 0; dt < 2; ++dt) {
            const int d = dt * 16 + col;
            av[dt] = *(const bf16x8*)&v_t[d * 64 + (((kk * 4 + quad) ^ (d & 7)) << 3)];
        }
        #pragma unroll
        for (int nt = 0; nt < 4; ++nt) {
            union { u16x8 u; bf16x8 b; } pk;
            #pragma unroll
            for (int j = 0; j < 4; ++j) {
                pk.u[j]     = f2b(sacc[kk * 2][nt][j]);
                pk.u[j + 4] = f2b(sacc[kk * 2 + 1][nt][j]);
            }
            #pragma unroll
            for (int dt = 0; dt < 2; ++dt)
                oacc[dt][nt] = __builtin_amdgcn_mfma_f32_16x16x32_bf16(
                    av[dt], pk.b, oacc[dt][nt], 0, 0, 0);
        }
    }
    #pragma unroll
    for (int dt = 0; dt < 2; ++dt)
        #pragma unroll
        for (int qt = 0; qt < 4; ++qt) {
            const int t = qt * 16 + col;
            u16x4 ov;
            #pragma unroll
            for (int r = 0; r < 4; ++r) ov[r] = f2b(oacc[dt][qt][r]);
            *(u16x4*)&wout_g[((size_t)win * 64 + t) * 256 + h * 32 + dt * 16 + quad * 4] = ov;
        }
}

// ---------------------------------------------------------------- proj ----
// R7/R8 verbatim: operand-swapped GEMM, direct float4 stores.
__global__ __launch_bounds__(256, 4) void k_proj(
    const u16* __restrict__ wout_g, const u16* __restrict__ wv_g,
    const float* __restrict__ pe_w, const float* __restrict__ pe_b,
    const u16* __restrict__ pjw, const float* __restrict__ pjb,
    float* __restrict__ out) {
    __shared__ __align__(16) u16 y_s[64 * 256];
    const int win = blockIdx.x;
    const int b = win >> 8;
    const int h0 = ((win >> 4) & 15) * 8;
    const int w0 = (win & 15) * 8;
    const int tid = threadIdx.x;
    const int cg = tid & 31, ch = cg * 8;
    const int psub = tid >> 5;

    float pw[9][8];
    #pragma unroll
    for (int j = 0; j < 8; ++j)
        #pragma unroll
        for (int k = 0; k < 9; ++k) pw[k][j] = pe_w[(ch + j) * 9 + k];
    float pb[8];
    #pragma unroll
    for (int j = 0; j < 8; ++j) pb[j] = pe_b[ch + j];

    for (int it = 0; it < 8; ++it) {
        const int p = it * 8 + psub;
        const int gh = h0 + (p >> 3), gw = w0 + (p & 7);
        float a[8];
        {
            const bf16x8 ov = *(const bf16x8*)&wout_g[((size_t)win * 64 + p) * 256 + ch];
            #pragma unroll
            for (int j = 0; j < 8; ++j) a[j] = b2f((u16)ov[j]) + pb[j];
        }
        #pragma unroll
        for (int dy = -1; dy <= 1; ++dy)
            #pragma unroll
            for (int dx = -1; dx <= 1; ++dx) {
                const int hh = gh + dy, ww2 = gw + dx;
                if (hh < 0 || hh >= 128 || ww2 < 0 || ww2 >= 128) continue;
                const int nwin = b * 256 + (hh >> 3) * 16 + (ww2 >> 3);
                const int ntk = (hh & 7) * 8 + (ww2 & 7);
                const bf16x8 vv = *(const bf16x8*)&wv_g[((size_t)nwin * 64 + ntk) * 256 + ch];
                const int k = (dy + 1) * 3 + (dx + 1);
                #pragma unroll
                for (int j = 0; j < 8; ++j) a[j] += b2f((u16)vv[j]) * pw[k][j];
            }
        u16x8 tmp;
        #pragma unroll
        for (int j = 0; j < 8; ++j) tmp[j] = f2b(a[j]);
        *(u16x8*)&y_s[p * 256 + (((ch >> 3) ^ (p & 7)) << 3)] = tmp;
    }
    __syncthreads();

    const int wave = tid >> 6, l = tid & 63;
    const int col = l & 15, quad = l >> 4;
    const f32x4 zero4 = {0.f, 0.f, 0.f, 0.f};
    f32x4 macc[4][4];                    // [pt(tok)][ot(och)]
    #pragma unroll
    for (int pt = 0; pt < 4; ++pt)
        #pragma unroll
        for (int ot = 0; ot < 4; ++ot) macc[pt][ot] = zero4;
    const int ob = wave * 64;
    for (int kk = 0; kk < 8; ++kk) {
        const int cb = kk * 32 + quad * 8;
        bf16x8 aw[4], by[4];
        #pragma unroll
        for (int ot = 0; ot < 4; ++ot)
            aw[ot] = *(const bf16x8*)&pjw[(size_t)(ob + ot * 16 + col) * 256 + cb];
        #pragma unroll
        for (int pt = 0; pt < 4; ++pt) {
            const int p = pt * 16 + col;
            by[pt] = *(const bf16x8*)&y_s[p * 256 + (((cb >> 3) ^ (p & 7)) << 3)];
        }
        #pragma unroll
        for (int pt = 0; pt < 4; ++pt)
            #pragma unroll
            for (int ot = 0; ot < 4; ++ot)
                macc[pt][ot] = __builtin_amdgcn_mfma_f32_16x16x32_bf16(
                    by[pt], aw[ot], macc[pt][ot], 0, 0, 0);
    }
    #pragma unroll
    for (int ot = 0; ot < 4; ++ot) {
        const int o = ob + ot * 16 + col;
        const float pbv = pjb[o];
        #pragma unroll
        for (int pt = 0; pt < 4; ++pt) {
            const int p0 = pt * 16 + quad * 4;
            float4 ov;
            ov.x = macc[pt][ot][0] + pbv;
            ov.y = macc[pt][ot][1] + pbv;
            ov.z = macc[pt][ot][2] + pbv;
            ov.w = macc[pt][ot][3] + pbv;
            *(float4*)&out[((size_t)(b * 256 + o)) * 16384 +
                           (h0 + (p0 >> 3)) * 128 + w0 + (p0 & 7)] = ov;
        }
    }
}

// -------------------------------------------------------------- launch ----
extern "C" void kernel_launch(void* const* d_in, const int* in_sizes, int n_in,
                              void* d_out, int out_size, void* d_ws, size_t ws_size,
                              hipStream_t stream) {
    const float* x    = (const float*)d_in[0];
    const float* qkvw = (const float*)d_in[1];
    const float* qkvb = (const float*)d_in[2];
    const float* pjw  = (const float*)d_in[3];
    const float* pjb  = (const float*)d_in[4];
    const float* pew  = (const float*)d_in[5];
    const float* peb  = (const float*)d_in[6];
    const float* lsc  = (const float*)d_in[7];
    const float* w1   = (const float*)d_in[8];
    const float* b1   = (const float*)d_in[9];
    const float* w2   = (const float*)d_in[10];

    char* ws = (char*)d_ws;
    u16* wv_b    = (u16*)(ws);                                    // 64 MiB
    u16* wout_b  = (u16*)(ws + (64ull << 20));                    // 64 MiB
    u16* qkvwb   = (u16*)(ws + (128ull << 20));                   // 384 KiB
    u16* pjwb    = (u16*)(ws + (128ull << 20) + 393216);          // 128 KiB
    float* biasT = (float*)(ws + (128ull << 20) + 393216 + 131072); // 128 KiB
    float* bt    = (float*)(ws + (128ull << 20) + 393216 + 262144); // 7.2 KiB

    // xt (swizzled bf16 x) lives in wout_b: dead until k_attn3 writes wout,
    // and k_qkv (its only reader) completes before k_attn3 starts.
    u16* xt = wout_b;
    // q/k scratch lives inside d_out; dead before k_proj overwrites d_out.
    u16* gq = (u16*)d_out;
    u16* gk = gq + 33554432u;

    hipLaunchKernelGGL(k_prep, dim3(768), dim3(256), 0, stream, qkvw, pjw, qkvwb, pjwb);
    hipLaunchKernelGGL(k_cpb,  dim3(1),   dim3(256), 0, stream, w1, b1, w2, bt);
    hipLaunchKernelGGL(k_bias, dim3(16),  dim3(256), 0, stream, bt, biasT);
    hipLaunchKernelGGL(k_xcvt, dim3(4096), dim3(256), 0, stream, x, xt);
    hipLaunchKernelGGL(k_qkv,  dim3(6144), dim3(256), 0, stream,
                       xt, qkvwb, qkvb, gq, gk, wv_b);
    hipLaunchKernelGGL(k_attn3, dim3(4096), dim3(256), 0, stream,
                       gq, gk, wv_b, lsc, biasT, wout_b);
    hipLaunchKernelGGL(k_proj, dim3(2048), dim3(256), 0, stream,
                       wout_b, wv_b, pew, peb, pjwb, pjb, (float*)d_out);
}

// Round 10
// 418.480 us; speedup vs baseline: 1.0963x; 1.0963x over previous
//
#include <hip/hip_runtime.h>

typedef unsigned short u16;
typedef unsigned int u32;
typedef short bf16x8 __attribute__((ext_vector_type(8)));
typedef float f32x4 __attribute__((ext_vector_type(4)));
typedef unsigned short u16x8 __attribute__((ext_vector_type(8)));
typedef unsigned short u16x4 __attribute__((ext_vector_type(4)));

#define DEVFN static __device__ __forceinline__

DEVFN u16 f2b(float f) {
    u32 u = __builtin_bit_cast(u32, f);
    u += 0x7FFFu + ((u >> 16) & 1u);
    return (u16)(u >> 16);
}
DEVFN float b2f(u16 h) {
    u32 u = ((u32)h) << 16;
    return __builtin_bit_cast(float, u);
}

typedef const __attribute__((address_space(1))) unsigned int glb_u32;
typedef __attribute__((address_space(3))) unsigned int lds_u32;
DEVFN void gload_lds16(const u16* g, u16* l) {
    __builtin_amdgcn_global_load_lds((glb_u32*)g, (lds_u32*)l, 16, 0, 0);
}

// ---------------------------------------------------------------- prep ----
__global__ void k_prep(const float* __restrict__ qkvw, const float* __restrict__ pjw,
                       u16* __restrict__ qkvwb, u16* __restrict__ pjwb) {
    int id = blockIdx.x * 256 + threadIdx.x;
    if (id < 196608) qkvwb[id] = f2b(qkvw[id]);
    if (id < 65536)  pjwb[id]  = f2b(pjw[id]);
}

__global__ void k_cpb(const float* __restrict__ w1, const float* __restrict__ b1,
                      const float* __restrict__ w2, float* __restrict__ bt) {
    int p = threadIdx.x;
    if (p >= 225) return;
    int d0 = p / 15, d1 = p % 15;
    float v0 = (float)(d0 - 7) * (8.0f / 7.0f);
    float v1 = (float)(d1 - 7) * (8.0f / 7.0f);
    float t0 = copysignf(log2f(fabsf(v0) + 1.0f) * (1.0f / 3.0f), v0);
    float t1 = copysignf(log2f(fabsf(v1) + 1.0f) * (1.0f / 3.0f), v1);
    float s[8] = {0.f, 0.f, 0.f, 0.f, 0.f, 0.f, 0.f, 0.f};
    for (int d = 0; d < 256; ++d) {
        float h = t0 * w1[2 * d] + t1 * w1[2 * d + 1] + b1[d];
        h = fmaxf(h, 0.0f);
        #pragma unroll
        for (int hh = 0; hh < 8; ++hh) s[hh] += h * w2[hh * 256 + d];
    }
    #pragma unroll
    for (int hh = 0; hh < 8; ++hh) bt[p * 8 + hh] = s[hh];
}

// TRANSPOSED bias table: biasT[h][k][q]
__global__ void k_bias(const float* __restrict__ bt, float* __restrict__ biasT) {
    int id = blockIdx.x * 256 + threadIdx.x;  // id = k*64 + q
    int kq = id >> 6, q = id & 63;
    int d0 = (q >> 3) - (kq >> 3) + 7;
    int d1 = (q & 7) - (kq & 7) + 7;
    int p = d0 * 15 + d1;
    #pragma unroll
    for (int h = 0; h < 8; ++h)
        biasT[h * 4096 + id] = 16.0f / (1.0f + expf(-bt[p * 8 + h]));
}

// ---------------------------------------------------------------- xcvt ----
// x fp32 NCHW -> bf16 in k_qkv's swizzled tile order. Lane map g=tid&7,
// tseg=tid>>3 so each store instruction fills whole 128B rows (8 g-lanes
// cover all 8 swizzle slots of one row; 8 tsegs -> 8 full lines/wave/instr).
__global__ __launch_bounds__(256) void k_xcvt(const float* __restrict__ x,
                                              u16* __restrict__ xt) {
    const int bid = blockIdx.x;              // 4096 = 1024 rowblk * 4 chunk
    const int c = bid & 3, rowblk = bid >> 2;
    const int tid = threadIdx.x;
    const int g = tid & 7;                   // 8-ch group 0..7
    const int tseg = tid >> 3;               // 0..31
    const int tok0 = tseg * 4;
    const float* src = x + ((size_t)(rowblk >> 7) * 256 + c * 64 + g * 8) * 16384
                         + (rowblk & 127) * 128 + tok0;
    float4 v[8];
    #pragma unroll
    for (int j = 0; j < 8; ++j)
        v[j] = *(const float4*)(src + (size_t)j * 16384);
    u16x8 o0, o1, o2, o3;
    #pragma unroll
    for (int j = 0; j < 8; ++j) {
        o0[j] = f2b(v[j].x);
        o1[j] = f2b(v[j].y);
        o2[j] = f2b(v[j].z);
        o3[j] = f2b(v[j].w);
    }
    const int s0 = g ^ ((tseg ^ (tok0 + 0)) & 7);
    const int s1 = g ^ ((tseg ^ (tok0 + 1)) & 7);
    const int s2 = g ^ ((tseg ^ (tok0 + 2)) & 7);
    const int s3 = g ^ ((tseg ^ (tok0 + 3)) & 7);
    u16* dst = xt + ((size_t)rowblk * 4 + c) * 8192;
    *(u16x8*)&dst[(tok0 + 0) * 64 + (s0 << 3)] = o0;
    *(u16x8*)&dst[(tok0 + 1) * 64 + (s1 << 3)] = o1;
    *(u16x8*)&dst[(tok0 + 2) * 64 + (s2 << 3)] = o2;
    *(u16x8*)&dst[(tok0 + 3) * 64 + (s3 << 3)] = o3;
}

// ---------------------------------------------------------------- qkv -----
// Staging via global_load_lds from pre-swizzled xt. __launch_bounds__(256,3):
// (256,4)'s 128-VGPR cap spills (R4/R6/R9 signature: VGPR=64, WRITE +73-146MB).
__global__ __launch_bounds__(256, 3) void k_qkv(
    const u16* __restrict__ xt, const u16* __restrict__ qkvw,
    const float* __restrict__ qkvb,
    u16* __restrict__ gq, u16* __restrict__ gk, u16* __restrict__ wv_g) {
    __shared__ __align__(16) u16 Xs[2][8192];  // [128 tok][64 ch] swizzled

    const int bid = blockIdx.x;                 // 6144 = 8 xcd * 128 rowblk * 6 ny
    const int xcd = bid & 7;
    const int idx = bid >> 3;
    const int ny = idx % 6;
    const int rowblk = xcd * 128 + idx / 6;
    const int b = rowblk >> 7, row = rowblk & 127;
    const int which = ny >> 1, half = ny & 1;

    const int tid = threadIdx.x;
    const int wave = tid >> 6, l = tid & 63, col = l & 15, quad = l >> 4;
    const int th = wave >> 1;
    const int oq = wave & 1;
    const int obase = half * 128 + oq * 64;

    int orow[4];
    #pragma unroll
    for (int nt = 0; nt < 4; ++nt) {
        const int oo = obase + nt * 16 + col;
        orow[nt] = (oo >> 5) * 96 + which * 32 + (oo & 31);
    }

    f32x4 acc[4][4];                            // [nt(och)][mt(tok)]
    #pragma unroll
    for (int i = 0; i < 4; ++i)
        #pragma unroll
        for (int j = 0; j < 4; ++j) acc[i][j] = f32x4{0.f, 0.f, 0.f, 0.f};

    const u16* xtb = xt + (size_t)rowblk * 32768;

    auto stage = [&](int c, int buf) {
        const u16* src = xtb + c * 8192 + wave * 2048 + l * 8;
        u16* dst = &Xs[buf][wave * 2048];
        #pragma unroll
        for (int i = 0; i < 4; ++i)
            gload_lds16(src + i * 512, dst + i * 512);
    };
    auto gemm = [&](int c, int buf) {
        #pragma unroll
        for (int kk = 0; kk < 2; ++kk) {
            const int cb = c * 64 + kk * 32 + quad * 8;
            const int lchunk = kk * 4 + quad;
            bf16x8 bw[4];
            #pragma unroll
            for (int nt = 0; nt < 4; ++nt)
                bw[nt] = *(const bf16x8*)&qkvw[(size_t)orow[nt] * 256 + cb];
            bf16x8 af[4];
            #pragma unroll
            for (int mt = 0; mt < 4; ++mt) {
                const int tok = th * 64 + mt * 16 + col;
                const int slot = lchunk ^ (((tok >> 2) ^ tok) & 7);
                af[mt] = *(const bf16x8*)&Xs[buf][tok * 64 + (slot << 3)];
            }
            #pragma unroll
            for (int nt = 0; nt < 4; ++nt)
                #pragma unroll
                for (int mt = 0; mt < 4; ++mt)
                    acc[nt][mt] = __builtin_amdgcn_mfma_f32_16x16x32_bf16(
                        bw[nt], af[mt], acc[nt][mt], 0, 0, 0);
        }
    };

    stage(0, 0);
    __syncthreads();
    #pragma unroll
    for (int c = 0; c < 4; ++c) {
        if (c < 3) stage(c + 1, (c + 1) & 1);   // prefetch next chunk (T14)
        gemm(c, c & 1);
        __syncthreads();                         // drains vmcnt (m97 pattern)
    }

    // epilogue: D[och][tok]
    const int hA = obase >> 5;
    f32x4 bqv[4];
    #pragma unroll
    for (int nt = 0; nt < 4; ++nt) {
        const int oo = obase + nt * 16 + quad * 4;
        bqv[nt] = *(const f32x4*)&qkvb[(oo >> 5) * 96 + which * 32 + (oo & 31)];
    }
    #pragma unroll
    for (int mt = 0; mt < 4; ++mt) {
        const int tok = th * 64 + mt * 16 + col;
        const int win = b * 256 + (row >> 3) * 16 + (tok >> 3);
        const int tk = (row & 7) * 8 + (tok & 7);
        float v[4][4];
        #pragma unroll
        for (int nt = 0; nt < 4; ++nt)
            #pragma unroll
            for (int r = 0; r < 4; ++r)
                v[nt][r] = acc[nt][mt][r] + bqv[nt][r];
        if (which < 2) {
            float sA = 0.f, sB = 0.f;
            #pragma unroll
            for (int r = 0; r < 4; ++r) {
                sA += v[0][r] * v[0][r] + v[1][r] * v[1][r];
                sB += v[2][r] * v[2][r] + v[3][r] * v[3][r];
            }
            sA += __shfl_xor(sA, 16, 64);
            sA += __shfl_xor(sA, 32, 64);
            sB += __shfl_xor(sB, 16, 64);
            sB += __shfl_xor(sB, 32, 64);
            const float iA = 1.0f / fmaxf(sqrtf(sA), 1e-12f);
            const float iB = 1.0f / fmaxf(sqrtf(sB), 1e-12f);
            #pragma unroll
            for (int r = 0; r < 4; ++r) {
                v[0][r] *= iA; v[1][r] *= iA;
                v[2][r] *= iB; v[3][r] *= iB;
            }
        }
        #pragma unroll
        for (int nt = 0; nt < 4; ++nt) {
            u16x4 ov;
            #pragma unroll
            for (int r = 0; r < 4; ++r) ov[r] = f2b(v[nt][r]);
            if (which == 2) {
                *(u16x4*)&wv_g[((size_t)win * 64 + tk) * 256 + obase + nt * 16 + quad * 4] = ov;
            } else {
                u16* G = (which == 0) ? gq : gk;
                const int h = hA + (nt >> 1);
                const int d = (nt & 1) * 16 + quad * 4;
                *(u16x4*)&G[((size_t)(win * 8 + h) * 64 + tk) * 32 + d] = ov;
            }
        }
    }
}

// ---------------------------------------------------------------- attn ----
// R8 verbatim: S^T layout, in-register softmax, P^T packed from regs.
__global__ __launch_bounds__(256, 3) void k_attn3(
    const u16* __restrict__ gq, const u16* __restrict__ gk,
    const u16* __restrict__ wv_g,
    const float* __restrict__ lsc, const float* __restrict__ biasT,
    u16* __restrict__ wout_g) {
    __shared__ __align__(16) u16 scr[4][2048];  // per wave: v_t only

    const int tid = threadIdx.x;
    const int wave = tid >> 6, l = tid & 63, col = l & 15, quad = l >> 4;
    const int job = blockIdx.x * 4 + wave;
    const int h = job >> 11, win = job & 2047;
    u16* const v_t = scr[wave];  // [32 d][64 pi-slot] swz(d&7)

    #pragma unroll
    for (int it = 0; it < 4; ++it) {
        const int idx = it * 64 + l;
        const int tok = idx & 63, dblk = idx >> 6;
        const u16x8 vv = *(const u16x8*)&wv_g[((size_t)win * 64 + tok) * 256 + h * 32 + dblk * 8];
        const int g = (tok >> 5) * 4 + ((tok >> 2) & 3);
        const int jj = ((tok >> 4) & 1) * 4 + (tok & 3);
        #pragma unroll
        for (int j = 0; j < 8; ++j) {
            const int d = dblk * 8 + j;
            v_t[d * 64 + (((g ^ (d & 7)) << 3) | jj)] = vv[j];
        }
    }

    const u16* const qbp = gq + (size_t)(win * 8 + h) * 2048;
    const u16* const kbp = gk + (size_t)(win * 8 + h) * 2048;
    bf16x8 ak[4], bq[4];
    #pragma unroll
    for (int mt = 0; mt < 4; ++mt)
        ak[mt] = *(const bf16x8*)&kbp[(mt * 16 + col) * 32 + quad * 8];
    #pragma unroll
    for (int nt = 0; nt < 4; ++nt)
        bq[nt] = *(const bf16x8*)&qbp[(nt * 16 + col) * 32 + quad * 8];

    const f32x4 zero4 = {0.f, 0.f, 0.f, 0.f};
    f32x4 sacc[4][4];
    #pragma unroll
    for (int mt = 0; mt < 4; ++mt)
        #pragma unroll
        for (int nt = 0; nt < 4; ++nt)
            sacc[mt][nt] = __builtin_amdgcn_mfma_f32_16x16x32_bf16(ak[mt], bq[nt], zero4, 0, 0, 0);

    const float ls = expf(fminf(lsc[h], 4.6051701859880914f));
    const float* bT = biasT + h * 4096;
    #pragma unroll
    for (int nt = 0; nt < 4; ++nt) {
        const int q = nt * 16 + col;
        float v[4][4];
        float mx = -1e30f;
        #pragma unroll
        for (int mt = 0; mt < 4; ++mt)
            #pragma unroll
            for (int r = 0; r < 4; ++r) {
                v[mt][r] = sacc[mt][nt][r] * ls + bT[(mt * 16 + quad * 4 + r) * 64 + q];
                mx = fmaxf(mx, v[mt][r]);
            }
        mx = fmaxf(mx, __shfl_xor(mx, 16, 64));
        mx = fmaxf(mx, __shfl_xor(mx, 32, 64));
        float s = 0.f;
        #pragma unroll
        for (int mt = 0; mt < 4; ++mt)
            #pragma unroll
            for (int r = 0; r < 4; ++r) {
                v[mt][r] = expf(v[mt][r] - mx);
                s += v[mt][r];
            }
        s += __shfl_xor(s, 16, 64);
        s += __shfl_xor(s, 32, 64);
        const float inv = 1.0f / s;
        #pragma unroll
        for (int mt = 0; mt < 4; ++mt)
            #pragma unroll
            for (int r = 0; r < 4; ++r)
                sacc[mt][nt][r] = v[mt][r] * inv;
    }

    f32x4 oacc[2][4];
    #pragma unroll
    for (int i = 0; i < 2; ++i)
        #pragma unroll
        for (int j = 0; j < 4; ++j) oacc[i][j] = zero4;
    #pragma unroll
    for (int kk = 0; kk < 2; ++kk) {
        bf16x8 av[2];
        #pragma unroll
        for (int dt = 0; dt < 2; ++dt) {
            const int d = dt * 16 + col;
            av[dt] = *(const bf16x8*)&v_t[d * 64 + (((kk * 4 + quad) ^ (d & 7)) << 3)];
        }
        #pragma unroll
        for (int nt = 0; nt < 4; ++nt) {
            union { u16x8 u; bf16x8 b; } pk;
            #pragma unroll
            for (int j = 0; j < 4; ++j) {
                pk.u[j]     = f2b(sacc[kk * 2][nt][j]);
                pk.u[j + 4] = f2b(sacc[kk * 2 + 1][nt][j]);
            }
            #pragma unroll
            for (int dt = 0; dt < 2; ++dt)
                oacc[dt][nt] = __builtin_amdgcn_mfma_f32_16x16x32_bf16(
                    av[dt], pk.b, oacc[dt][nt], 0, 0, 0);
        }
    }
    #pragma unroll
    for (int dt = 0; dt < 2; ++dt)
        #pragma unroll
        for (int qt = 0; qt < 4; ++qt) {
            const int t = qt * 16 + col;
            u16x4 ov;
            #pragma unroll
            for (int r = 0; r < 4; ++r) ov[r] = f2b(oacc[dt][qt][r]);
            *(u16x4*)&wout_g[((size_t)win * 64 + t) * 256 + h * 32 + dt * 16 + quad * 4] = ov;
        }
}

// ---------------------------------------------------------------- proj ----
// R7/R8 verbatim: operand-swapped GEMM, direct float4 stores.
__global__ __launch_bounds__(256, 4) void k_proj(
    const u16* __restrict__ wout_g, const u16* __restrict__ wv_g,
    const float* __restrict__ pe_w, const float* __restrict__ pe_b,
    const u16* __restrict__ pjw, const float* __restrict__ pjb,
    float* __restrict__ out) {
    __shared__ __align__(16) u16 y_s[64 * 256];
    const int win = blockIdx.x;
    const int b = win >> 8;
    const int h0 = ((win >> 4) & 15) * 8;
    const int w0 = (win & 15) * 8;
    const int tid = threadIdx.x;
    const int cg = tid & 31, ch = cg * 8;
    const int psub = tid >> 5;

    float pw[9][8];
    #pragma unroll
    for (int j = 0; j < 8; ++j)
        #pragma unroll
        for (int k = 0; k < 9; ++k) pw[k][j] = pe_w[(ch + j) * 9 + k];
    float pb[8];
    #pragma unroll
    for (int j = 0; j < 8; ++j) pb[j] = pe_b[ch + j];

    for (int it = 0; it < 8; ++it) {
        const int p = it * 8 + psub;
        const int gh = h0 + (p >> 3), gw = w0 + (p & 7);
        float a[8];
        {
            const bf16x8 ov = *(const bf16x8*)&wout_g[((size_t)win * 64 + p) * 256 + ch];
            #pragma unroll
            for (int j = 0; j < 8; ++j) a[j] = b2f((u16)ov[j]) + pb[j];
        }
        #pragma unroll
        for (int dy = -1; dy <= 1; ++dy)
            #pragma unroll
            for (int dx = -1; dx <= 1; ++dx) {
                const int hh = gh + dy, ww2 = gw + dx;
                if (hh < 0 || hh >= 128 || ww2 < 0 || ww2 >= 128) continue;
                const int nwin = b * 256 + (hh >> 3) * 16 + (ww2 >> 3);
                const int ntk = (hh & 7) * 8 + (ww2 & 7);
                const bf16x8 vv = *(const bf16x8*)&wv_g[((size_t)nwin * 64 + ntk) * 256 + ch];
                const int k = (dy + 1) * 3 + (dx + 1);
                #pragma unroll
                for (int j = 0; j < 8; ++j) a[j] += b2f((u16)vv[j]) * pw[k][j];
            }
        u16x8 tmp;
        #pragma unroll
        for (int j = 0; j < 8; ++j) tmp[j] = f2b(a[j]);
        *(u16x8*)&y_s[p * 256 + (((ch >> 3) ^ (p & 7)) << 3)] = tmp;
    }
    __syncthreads();

    const int wave = tid >> 6, l = tid & 63;
    const int col = l & 15, quad = l >> 4;
    const f32x4 zero4 = {0.f, 0.f, 0.f, 0.f};
    f32x4 macc[4][4];                    // [pt(tok)][ot(och)]
    #pragma unroll
    for (int pt = 0; pt < 4; ++pt)
        #pragma unroll
        for (int ot = 0; ot < 4; ++ot) macc[pt][ot] = zero4;
    const int ob = wave * 64;
    for (int kk = 0; kk < 8; ++kk) {
        const int cb = kk * 32 + quad * 8;
        bf16x8 aw[4], by[4];
        #pragma unroll
        for (int ot = 0; ot < 4; ++ot)
            aw[ot] = *(const bf16x8*)&pjw[(size_t)(ob + ot * 16 + col) * 256 + cb];
        #pragma unroll
        for (int pt = 0; pt < 4; ++pt) {
            const int p = pt * 16 + col;
            by[pt] = *(const bf16x8*)&y_s[p * 256 + (((cb >> 3) ^ (p & 7)) << 3)];
        }
        #pragma unroll
        for (int pt = 0; pt < 4; ++pt)
            #pragma unroll
            for (int ot = 0; ot < 4; ++ot)
                macc[pt][ot] = __builtin_amdgcn_mfma_f32_16x16x32_bf16(
                    by[pt], aw[ot], macc[pt][ot], 0, 0, 0);
    }
    #pragma unroll
    for (int ot = 0; ot < 4; ++ot) {
        const int o = ob + ot * 16 + col;
        const float pbv = pjb[o];
        #pragma unroll
        for (int pt = 0; pt < 4; ++pt) {
            const int p0 = pt * 16 + quad * 4;
            float4 ov;
            ov.x = macc[pt][ot][0] + pbv;
            ov.y = macc[pt][ot][1] + pbv;
            ov.z = macc[pt][ot][2] + pbv;
            ov.w = macc[pt][ot][3] + pbv;
            *(float4*)&out[((size_t)(b * 256 + o)) * 16384 +
                           (h0 + (p0 >> 3)) * 128 + w0 + (p0 & 7)] = ov;
        }
    }
}

// -------------------------------------------------------------- launch ----
extern "C" void kernel_launch(void* const* d_in, const int* in_sizes, int n_in,
                              void* d_out, int out_size, void* d_ws, size_t ws_size,
                              hipStream_t stream) {
    const float* x    = (const float*)d_in[0];
    const float* qkvw = (const float*)d_in[1];
    const float* qkvb = (const float*)d_in[2];
    const float* pjw  = (const float*)d_in[3];
    const float* pjb  = (const float*)d_in[4];
    const float* pew  = (const float*)d_in[5];
    const float* peb  = (const float*)d_in[6];
    const float* lsc  = (const float*)d_in[7];
    const float* w1   = (const float*)d_in[8];
    const float* b1   = (const float*)d_in[9];
    const float* w2   = (const float*)d_in[10];

    char* ws = (char*)d_ws;
    u16* wv_b    = (u16*)(ws);                                    // 64 MiB
    u16* wout_b  = (u16*)(ws + (64ull << 20));                    // 64 MiB
    u16* qkvwb   = (u16*)(ws + (128ull << 20));                   // 384 KiB
    u16* pjwb    = (u16*)(ws + (128ull << 20) + 393216);          // 128 KiB
    float* biasT = (float*)(ws + (128ull << 20) + 393216 + 131072); // 128 KiB
    float* bt    = (float*)(ws + (128ull << 20) + 393216 + 262144); // 7.2 KiB

    // xt (swizzled bf16 x) lives in wout_b: dead until k_attn3 writes wout,
    // and k_qkv (its only reader) completes before k_attn3 starts.
    u16* xt = wout_b;
    // q/k scratch lives inside d_out; dead before k_proj overwrites d_out.
    u16* gq = (u16*)d_out;
    u16* gk = gq + 33554432u;

    hipLaunchKernelGGL(k_prep, dim3(768), dim3(256), 0, stream, qkvw, pjw, qkvwb, pjwb);
    hipLaunchKernelGGL(k_cpb,  dim3(1),   dim3(256), 0, stream, w1, b1, w2, bt);
    hipLaunchKernelGGL(k_bias, dim3(16),  dim3(256), 0, stream, bt, biasT);
    hipLaunchKernelGGL(k_xcvt, dim3(4096), dim3(256), 0, stream, x, xt);
    hipLaunchKernelGGL(k_qkv,  dim3(6144), dim3(256), 0, stream,
                       xt, qkvwb, qkvb, gq, gk, wv_b);
    hipLaunchKernelGGL(k_attn3, dim3(4096), dim3(256), 0, stream,
                       gq, gk, wv_b, lsc, biasT, wout_b);
    hipLaunchKernelGGL(k_proj, dim3(2048), dim3(256), 0, stream,
                       wout_b, wv_b, pew, peb, pjwb, pjb, (float*)d_out);
}

// Round 11
// 387.294 us; speedup vs baseline: 1.1846x; 1.0805x over previous
//
#include <hip/hip_runtime.h>

typedef unsigned short u16;
typedef unsigned int u32;
typedef short bf16x8 __attribute__((ext_vector_type(8)));
typedef float f32x4 __attribute__((ext_vector_type(4)));
typedef unsigned short u16x8 __attribute__((ext_vector_type(8)));
typedef unsigned short u16x4 __attribute__((ext_vector_type(4)));

#define DEVFN static __device__ __forceinline__

DEVFN u16 f2b(float f) {
    u32 u = __builtin_bit_cast(u32, f);
    u += 0x7FFFu + ((u >> 16) & 1u);
    return (u16)(u >> 16);
}
DEVFN float b2f(u16 h) {
    u32 u = ((u32)h) << 16;
    return __builtin_bit_cast(float, u);
}

typedef const __attribute__((address_space(1))) unsigned int glb_u32;
typedef __attribute__((address_space(3))) unsigned int lds_u32;
DEVFN void gload_lds16(const u16* g, u16* l) {
    __builtin_amdgcn_global_load_lds((glb_u32*)g, (lds_u32*)l, 16, 0, 0);
}

// ---------------------------------------------------------------- prep ----
__global__ void k_prep(const float* __restrict__ qkvw, const float* __restrict__ pjw,
                       u16* __restrict__ qkvwb, u16* __restrict__ pjwb) {
    int id = blockIdx.x * 256 + threadIdx.x;
    if (id < 196608) qkvwb[id] = f2b(qkvw[id]);
    if (id < 65536)  pjwb[id]  = f2b(pjw[id]);
}

__global__ void k_cpb(const float* __restrict__ w1, const float* __restrict__ b1,
                      const float* __restrict__ w2, float* __restrict__ bt) {
    int p = threadIdx.x;
    if (p >= 225) return;
    int d0 = p / 15, d1 = p % 15;
    float v0 = (float)(d0 - 7) * (8.0f / 7.0f);
    float v1 = (float)(d1 - 7) * (8.0f / 7.0f);
    float t0 = copysignf(log2f(fabsf(v0) + 1.0f) * (1.0f / 3.0f), v0);
    float t1 = copysignf(log2f(fabsf(v1) + 1.0f) * (1.0f / 3.0f), v1);
    float s[8] = {0.f, 0.f, 0.f, 0.f, 0.f, 0.f, 0.f, 0.f};
    for (int d = 0; d < 256; ++d) {
        float h = t0 * w1[2 * d] + t1 * w1[2 * d + 1] + b1[d];
        h = fmaxf(h, 0.0f);
        #pragma unroll
        for (int hh = 0; hh < 8; ++hh) s[hh] += h * w2[hh * 256 + d];
    }
    #pragma unroll
    for (int hh = 0; hh < 8; ++hh) bt[p * 8 + hh] = s[hh];
}

// TRANSPOSED bias table: biasT[h][k][q]
__global__ void k_bias(const float* __restrict__ bt, float* __restrict__ biasT) {
    int id = blockIdx.x * 256 + threadIdx.x;  // id = k*64 + q
    int kq = id >> 6, q = id & 63;
    int d0 = (q >> 3) - (kq >> 3) + 7;
    int d1 = (q & 7) - (kq & 7) + 7;
    int p = d0 * 15 + d1;
    #pragma unroll
    for (int h = 0; h < 8; ++h)
        biasT[h * 4096 + id] = 16.0f / (1.0f + expf(-bt[p * 8 + h]));
}

// ---------------------------------------------------------------- xcvt ----
// x fp32 NCHW -> bf16 in k_qkv's swizzled tile order. XCD-aligned: block
// writing rowblk runs on XCD rowblk>>7 — same XCD that reads it in k_qkv.
__global__ __launch_bounds__(256) void k_xcvt(const float* __restrict__ x,
                                              u16* __restrict__ xt) {
    const int bid = blockIdx.x;              // 4096 = 8 xcd * 128 rowblk * 4 chunk
    const int xcd = bid & 7;
    const int i = bid >> 3;                  // 0..511
    const int rowblk = xcd * 128 + (i >> 2);
    const int c = i & 3;
    const int tid = threadIdx.x;
    const int g = tid & 7;                   // 8-ch group 0..7
    const int tseg = tid >> 3;               // 0..31
    const int tok0 = tseg * 4;
    const float* src = x + ((size_t)(rowblk >> 7) * 256 + c * 64 + g * 8) * 16384
                         + (rowblk & 127) * 128 + tok0;
    float4 v[8];
    #pragma unroll
    for (int j = 0; j < 8; ++j)
        v[j] = *(const float4*)(src + (size_t)j * 16384);
    u16x8 o0, o1, o2, o3;
    #pragma unroll
    for (int j = 0; j < 8; ++j) {
        o0[j] = f2b(v[j].x);
        o1[j] = f2b(v[j].y);
        o2[j] = f2b(v[j].z);
        o3[j] = f2b(v[j].w);
    }
    const int s0 = g ^ ((tseg ^ (tok0 + 0)) & 7);
    const int s1 = g ^ ((tseg ^ (tok0 + 1)) & 7);
    const int s2 = g ^ ((tseg ^ (tok0 + 2)) & 7);
    const int s3 = g ^ ((tseg ^ (tok0 + 3)) & 7);
    u16* dst = xt + ((size_t)rowblk * 4 + c) * 8192;
    *(u16x8*)&dst[(tok0 + 0) * 64 + (s0 << 3)] = o0;
    *(u16x8*)&dst[(tok0 + 1) * 64 + (s1 << 3)] = o1;
    *(u16x8*)&dst[(tok0 + 2) * 64 + (s2 << 3)] = o2;
    *(u16x8*)&dst[(tok0 + 3) * 64 + (s3 << 3)] = o3;
}

// ---------------------------------------------------------------- qkv -----
// gload_lds staging + weight-register double-buffer (R8 pattern): chunk c+1's
// weights load during gemm(c) so no in-loop L2 latency exposure.
__global__ __launch_bounds__(256, 3) void k_qkv(
    const u16* __restrict__ xt, const u16* __restrict__ qkvw,
    const float* __restrict__ qkvb,
    u16* __restrict__ gq, u16* __restrict__ gk, u16* __restrict__ wv_g) {
    __shared__ __align__(16) u16 Xs[2][8192];  // [128 tok][64 ch] swizzled

    const int bid = blockIdx.x;                 // 6144 = 8 xcd * 128 rowblk * 6 ny
    const int xcd = bid & 7;
    const int idx = bid >> 3;
    const int ny = idx % 6;
    const int rowblk = xcd * 128 + idx / 6;
    const int b = rowblk >> 7, row = rowblk & 127;
    const int which = ny >> 1, half = ny & 1;

    const int tid = threadIdx.x;
    const int wave = tid >> 6, l = tid & 63, col = l & 15, quad = l >> 4;
    const int th = wave >> 1;
    const int oq = wave & 1;
    const int obase = half * 128 + oq * 64;

    int orow[4];
    #pragma unroll
    for (int nt = 0; nt < 4; ++nt) {
        const int oo = obase + nt * 16 + col;
        orow[nt] = (oo >> 5) * 96 + which * 32 + (oo & 31);
    }

    f32x4 acc[4][4];                            // [nt(och)][mt(tok)]
    #pragma unroll
    for (int i = 0; i < 4; ++i)
        #pragma unroll
        for (int j = 0; j < 4; ++j) acc[i][j] = f32x4{0.f, 0.f, 0.f, 0.f};

    const u16* xtb = xt + (size_t)rowblk * 32768;

    auto stage = [&](int c, int buf) {
        const u16* src = xtb + c * 8192 + wave * 2048 + l * 8;
        u16* dst = &Xs[buf][wave * 2048];
        #pragma unroll
        for (int i = 0; i < 4; ++i)
            gload_lds16(src + i * 512, dst + i * 512);
    };
    auto loadW = [&](int c, bf16x8* bw) {
        #pragma unroll
        for (int kk = 0; kk < 2; ++kk)
            #pragma unroll
            for (int nt = 0; nt < 4; ++nt)
                bw[kk * 4 + nt] = *(const bf16x8*)&qkvw[(size_t)orow[nt] * 256 +
                                                        c * 64 + kk * 32 + quad * 8];
    };
    auto gemm = [&](int buf, const bf16x8* bw) {
        #pragma unroll
        for (int kk = 0; kk < 2; ++kk) {
            const int lchunk = kk * 4 + quad;
            bf16x8 af[4];
            #pragma unroll
            for (int mt = 0; mt < 4; ++mt) {
                const int tok = th * 64 + mt * 16 + col;
                const int slot = lchunk ^ (((tok >> 2) ^ tok) & 7);
                af[mt] = *(const bf16x8*)&Xs[buf][tok * 64 + (slot << 3)];
            }
            #pragma unroll
            for (int nt = 0; nt < 4; ++nt)
                #pragma unroll
                for (int mt = 0; mt < 4; ++mt)
                    acc[nt][mt] = __builtin_amdgcn_mfma_f32_16x16x32_bf16(
                        bw[kk * 4 + nt], af[mt], acc[nt][mt], 0, 0, 0);
        }
    };

    bf16x8 bwA[8], bwB[8];
    stage(0, 0);
    loadW(0, bwA);
    __syncthreads();
    #pragma unroll
    for (int c = 0; c < 4; ++c) {
        if (c < 3) {
            stage(c + 1, (c + 1) & 1);          // async prefetch (T14)
            loadW(c + 1, (c & 1) ? bwA : bwB);  // weight prefetch
        }
        gemm(c & 1, (c & 1) ? bwB : bwA);
        __syncthreads();
    }

    // epilogue: D[och][tok]
    const int hA = obase >> 5;
    f32x4 bqv[4];
    #pragma unroll
    for (int nt = 0; nt < 4; ++nt) {
        const int oo = obase + nt * 16 + quad * 4;
        bqv[nt] = *(const f32x4*)&qkvb[(oo >> 5) * 96 + which * 32 + (oo & 31)];
    }
    #pragma unroll
    for (int mt = 0; mt < 4; ++mt) {
        const int tok = th * 64 + mt * 16 + col;
        const int win = b * 256 + (row >> 3) * 16 + (tok >> 3);
        const int tk = (row & 7) * 8 + (tok & 7);
        float v[4][4];
        #pragma unroll
        for (int nt = 0; nt < 4; ++nt)
            #pragma unroll
            for (int r = 0; r < 4; ++r)
                v[nt][r] = acc[nt][mt][r] + bqv[nt][r];
        if (which < 2) {
            float sA = 0.f, sB = 0.f;
            #pragma unroll
            for (int r = 0; r < 4; ++r) {
                sA += v[0][r] * v[0][r] + v[1][r] * v[1][r];
                sB += v[2][r] * v[2][r] + v[3][r] * v[3][r];
            }
            sA += __shfl_xor(sA, 16, 64);
            sA += __shfl_xor(sA, 32, 64);
            sB += __shfl_xor(sB, 16, 64);
            sB += __shfl_xor(sB, 32, 64);
            const float iA = 1.0f / fmaxf(sqrtf(sA), 1e-12f);
            const float iB = 1.0f / fmaxf(sqrtf(sB), 1e-12f);
            #pragma unroll
            for (int r = 0; r < 4; ++r) {
                v[0][r] *= iA; v[1][r] *= iA;
                v[2][r] *= iB; v[3][r] *= iB;
            }
        }
        #pragma unroll
        for (int nt = 0; nt < 4; ++nt) {
            u16x4 ov;
            #pragma unroll
            for (int r = 0; r < 4; ++r) ov[r] = f2b(v[nt][r]);
            if (which == 2) {
                *(u16x4*)&wv_g[((size_t)win * 64 + tk) * 256 + obase + nt * 16 + quad * 4] = ov;
            } else {
                u16* G = (which == 0) ? gq : gk;
                const int h = hA + (nt >> 1);
                const int d = (nt & 1) * 16 + quad * 4;
                *(u16x4*)&G[((size_t)(win * 8 + h) * 64 + tk) * 32 + d] = ov;
            }
        }
    }
}

// ---------------------------------------------------------------- attn ----
// R8 structure; XCD-aligned job map: win>>8 == xcd == writer's XCD.
__global__ __launch_bounds__(256, 3) void k_attn3(
    const u16* __restrict__ gq, const u16* __restrict__ gk,
    const u16* __restrict__ wv_g,
    const float* __restrict__ lsc, const float* __restrict__ biasT,
    u16* __restrict__ wout_g) {
    __shared__ __align__(16) u16 scr[4][2048];  // per wave: v_t only

    const int tid = threadIdx.x;
    const int wave = tid >> 6, l = tid & 63, col = l & 15, quad = l >> 4;
    const int bid = blockIdx.x;                 // 4096 = 8 xcd * 512
    const int xcd = bid & 7;
    const int jl = (bid >> 3) * 4 + wave;       // 0..2047 per xcd
    const int h = jl >> 8;
    const int win = xcd * 256 + (jl & 255);
    u16* const v_t = scr[wave];  // [32 d][64 pi-slot] swz(d&7)

    #pragma unroll
    for (int it = 0; it < 4; ++it) {
        const int idx = it * 64 + l;
        const int tok = idx & 63, dblk = idx >> 6;
        const u16x8 vv = *(const u16x8*)&wv_g[((size_t)win * 64 + tok) * 256 + h * 32 + dblk * 8];
        const int g = (tok >> 5) * 4 + ((tok >> 2) & 3);
        const int jj = ((tok >> 4) & 1) * 4 + (tok & 3);
        #pragma unroll
        for (int j = 0; j < 8; ++j) {
            const int d = dblk * 8 + j;
            v_t[d * 64 + (((g ^ (d & 7)) << 3) | jj)] = vv[j];
        }
    }

    const u16* const qbp = gq + (size_t)(win * 8 + h) * 2048;
    const u16* const kbp = gk + (size_t)(win * 8 + h) * 2048;
    bf16x8 ak[4], bq[4];
    #pragma unroll
    for (int mt = 0; mt < 4; ++mt)
        ak[mt] = *(const bf16x8*)&kbp[(mt * 16 + col) * 32 + quad * 8];
    #pragma unroll
    for (int nt = 0; nt < 4; ++nt)
        bq[nt] = *(const bf16x8*)&qbp[(nt * 16 + col) * 32 + quad * 8];

    const f32x4 zero4 = {0.f, 0.f, 0.f, 0.f};
    f32x4 sacc[4][4];
    #pragma unroll
    for (int mt = 0; mt < 4; ++mt)
        #pragma unroll
        for (int nt = 0; nt < 4; ++nt)
            sacc[mt][nt] = __builtin_amdgcn_mfma_f32_16x16x32_bf16(ak[mt], bq[nt], zero4, 0, 0, 0);

    const float ls = expf(fminf(lsc[h], 4.6051701859880914f));
    const float* bT = biasT + h * 4096;
    #pragma unroll
    for (int nt = 0; nt < 4; ++nt) {
        const int q = nt * 16 + col;
        float v[4][4];
        float mx = -1e30f;
        #pragma unroll
        for (int mt = 0; mt < 4; ++mt)
            #pragma unroll
            for (int r = 0; r < 4; ++r) {
                v[mt][r] = sacc[mt][nt][r] * ls + bT[(mt * 16 + quad * 4 + r) * 64 + q];
                mx = fmaxf(mx, v[mt][r]);
            }
        mx = fmaxf(mx, __shfl_xor(mx, 16, 64));
        mx = fmaxf(mx, __shfl_xor(mx, 32, 64));
        float s = 0.f;
        #pragma unroll
        for (int mt = 0; mt < 4; ++mt)
            #pragma unroll
            for (int r = 0; r < 4; ++r) {
                v[mt][r] = expf(v[mt][r] - mx);
                s += v[mt][r];
            }
        s += __shfl_xor(s, 16, 64);
        s += __shfl_xor(s, 32, 64);
        const float inv = 1.0f / s;
        #pragma unroll
        for (int mt = 0; mt < 4; ++mt)
            #pragma unroll
            for (int r = 0; r < 4; ++r)
                sacc[mt][nt][r] = v[mt][r] * inv;
    }

    f32x4 oacc[2][4];
    #pragma unroll
    for (int i = 0; i < 2; ++i)
        #pragma unroll
        for (int j = 0; j < 4; ++j) oacc[i][j] = zero4;
    #pragma unroll
    for (int kk = 0; kk < 2; ++kk) {
        bf16x8 av[2];
        #pragma unroll
        for (int dt = 0; dt < 2; ++dt) {
            const int d = dt * 16 + col;
            av[dt] = *(const bf16x8*)&v_t[d * 64 + (((kk * 4 + quad) ^ (d & 7)) << 3)];
        }
        #pragma unroll
        for (int nt = 0; nt < 4; ++nt) {
            union { u16x8 u; bf16x8 b; } pk;
            #pragma unroll
            for (int j = 0; j < 4; ++j) {
                pk.u[j]     = f2b(sacc[kk * 2][nt][j]);
                pk.u[j + 4] = f2b(sacc[kk * 2 + 1][nt][j]);
            }
            #pragma unroll
            for (int dt = 0; dt < 2; ++dt)
                oacc[dt][nt] = __builtin_amdgcn_mfma_f32_16x16x32_bf16(
                    av[dt], pk.b, oacc[dt][nt], 0, 0, 0);
        }
    }
    #pragma unroll
    for (int dt = 0; dt < 2; ++dt)
        #pragma unroll
        for (int qt = 0; qt < 4; ++qt) {
            const int t = qt * 16 + col;
            u16x4 ov;
            #pragma unroll
            for (int r = 0; r < 4; ++r) ov[r] = f2b(oacc[dt][qt][r]);
            *(u16x4*)&wout_g[((size_t)win * 64 + t) * 256 + h * 32 + dt * 16 + quad * 4] = ov;
        }
}

// ---------------------------------------------------------------- proj ----
// R7/R8 structure; XCD-aligned win map (win>>8 == xcd == writer's XCD;
// dwconv halo neighbors share the image -> same XCD).
__global__ __launch_bounds__(256, 4) void k_proj(
    const u16* __restrict__ wout_g, const u16* __restrict__ wv_g,
    const float* __restrict__ pe_w, const float* __restrict__ pe_b,
    const u16* __restrict__ pjw, const float* __restrict__ pjb,
    float* __restrict__ out) {
    __shared__ __align__(16) u16 y_s[64 * 256];
    const int bid0 = blockIdx.x;                // 2048 = 8 xcd * 256
    const int win = (bid0 & 7) * 256 + (bid0 >> 3);
    const int b = win >> 8;
    const int h0 = ((win >> 4) & 15) * 8;
    const int w0 = (win & 15) * 8;
    const int tid = threadIdx.x;
    const int cg = tid & 31, ch = cg * 8;
    const int psub = tid >> 5;

    float pw[9][8];
    #pragma unroll
    for (int j = 0; j < 8; ++j)
        #pragma unroll
        for (int k = 0; k < 9; ++k) pw[k][j] = pe_w[(ch + j) * 9 + k];
    float pb[8];
    #pragma unroll
    for (int j = 0; j < 8; ++j) pb[j] = pe_b[ch + j];

    for (int it = 0; it < 8; ++it) {
        const int p = it * 8 + psub;
        const int gh = h0 + (p >> 3), gw = w0 + (p & 7);
        float a[8];
        {
            const bf16x8 ov = *(const bf16x8*)&wout_g[((size_t)win * 64 + p) * 256 + ch];
            #pragma unroll
            for (int j = 0; j < 8; ++j) a[j] = b2f((u16)ov[j]) + pb[j];
        }
        #pragma unroll
        for (int dy = -1; dy <= 1; ++dy)
            #pragma unroll
            for (int dx = -1; dx <= 1; ++dx) {
                const int hh = gh + dy, ww2 = gw + dx;
                if (hh < 0 || hh >= 128 || ww2 < 0 || ww2 >= 128) continue;
                const int nwin = b * 256 + (hh >> 3) * 16 + (ww2 >> 3);
                const int ntk = (hh & 7) * 8 + (ww2 & 7);
                const bf16x8 vv = *(const bf16x8*)&wv_g[((size_t)nwin * 64 + ntk) * 256 + ch];
                const int k = (dy + 1) * 3 + (dx + 1);
                #pragma unroll
                for (int j = 0; j < 8; ++j) a[j] += b2f((u16)vv[j]) * pw[k][j];
            }
        u16x8 tmp;
        #pragma unroll
        for (int j = 0; j < 8; ++j) tmp[j] = f2b(a[j]);
        *(u16x8*)&y_s[p * 256 + (((ch >> 3) ^ (p & 7)) << 3)] = tmp;
    }
    __syncthreads();

    const int wave = tid >> 6, l = tid & 63;
    const int col = l & 15, quad = l >> 4;
    const f32x4 zero4 = {0.f, 0.f, 0.f, 0.f};
    f32x4 macc[4][4];                    // [pt(tok)][ot(och)]
    #pragma unroll
    for (int pt = 0; pt < 4; ++pt)
        #pragma unroll
        for (int ot = 0; ot < 4; ++ot) macc[pt][ot] = zero4;
    const int ob = wave * 64;
    for (int kk = 0; kk < 8; ++kk) {
        const int cb = kk * 32 + quad * 8;
        bf16x8 aw[4], by[4];
        #pragma unroll
        for (int ot = 0; ot < 4; ++ot)
            aw[ot] = *(const bf16x8*)&pjw[(size_t)(ob + ot * 16 + col) * 256 + cb];
        #pragma unroll
        for (int pt = 0; pt < 4; ++pt) {
            const int p = pt * 16 + col;
            by[pt] = *(const bf16x8*)&y_s[p * 256 + (((cb >> 3) ^ (p & 7)) << 3)];
        }
        #pragma unroll
        for (int pt = 0; pt < 4; ++pt)
            #pragma unroll
            for (int ot = 0; ot < 4; ++ot)
                macc[pt][ot] = __builtin_amdgcn_mfma_f32_16x16x32_bf16(
                    by[pt], aw[ot], macc[pt][ot], 0, 0, 0);
    }
    #pragma unroll
    for (int ot = 0; ot < 4; ++ot) {
        const int o = ob + ot * 16 + col;
        const float pbv = pjb[o];
        #pragma unroll
        for (int pt = 0; pt < 4; ++pt) {
            const int p0 = pt * 16 + quad * 4;
            float4 ov;
            ov.x = macc[pt][ot][0] + pbv;
            ov.y = macc[pt][ot][1] + pbv;
            ov.z = macc[pt][ot][2] + pbv;
            ov.w = macc[pt][ot][3] + pbv;
            *(float4*)&out[((size_t)(b * 256 + o)) * 16384 +
                           (h0 + (p0 >> 3)) * 128 + w0 + (p0 & 7)] = ov;
        }
    }
}

// -------------------------------------------------------------- launch ----
extern "C" void kernel_launch(void* const* d_in, const int* in_sizes, int n_in,
                              void* d_out, int out_size, void* d_ws, size_t ws_size,
                              hipStream_t stream) {
    const float* x    = (const float*)d_in[0];
    const float* qkvw = (const float*)d_in[1];
    const float* qkvb = (const float*)d_in[2];
    const float* pjw  = (const float*)d_in[3];
    const float* pjb  = (const float*)d_in[4];
    const float* pew  = (const float*)d_in[5];
    const float* peb  = (const float*)d_in[6];
    const float* lsc  = (const float*)d_in[7];
    const float* w1   = (const float*)d_in[8];
    const float* b1   = (const float*)d_in[9];
    const float* w2   = (const float*)d_in[10];

    char* ws = (char*)d_ws;
    u16* wv_b    = (u16*)(ws);                                    // 64 MiB
    u16* wout_b  = (u16*)(ws + (64ull << 20));                    // 64 MiB
    u16* qkvwb   = (u16*)(ws + (128ull << 20));                   // 384 KiB
    u16* pjwb    = (u16*)(ws + (128ull << 20) + 393216);          // 128 KiB
    float* biasT = (float*)(ws + (128ull << 20) + 393216 + 131072); // 128 KiB
    float* bt    = (float*)(ws + (128ull << 20) + 393216 + 262144); // 7.2 KiB

    // xt (swizzled bf16 x) lives in wout_b: dead until k_attn3 writes wout,
    // and k_qkv (its only reader) completes before k_attn3 starts.
    u16* xt = wout_b;
    // q/k scratch lives inside d_out; dead before k_proj overwrites d_out.
    u16* gq = (u16*)d_out;
    u16* gk = gq + 33554432u;

    hipLaunchKernelGGL(k_prep, dim3(768), dim3(256), 0, stream, qkvw, pjw, qkvwb, pjwb);
    hipLaunchKernelGGL(k_cpb,  dim3(1),   dim3(256), 0, stream, w1, b1, w2, bt);
    hipLaunchKernelGGL(k_bias, dim3(16),  dim3(256), 0, stream, bt, biasT);
    hipLaunchKernelGGL(k_xcvt, dim3(4096), dim3(256), 0, stream, x, xt);
    hipLaunchKernelGGL(k_qkv,  dim3(6144), dim3(256), 0, stream,
                       xt, qkvwb, qkvb, gq, gk, wv_b);
    hipLaunchKernelGGL(k_attn3, dim3(4096), dim3(256), 0, stream,
                       gq, gk, wv_b, lsc, biasT, wout_b);
    hipLaunchKernelGGL(k_proj, dim3(2048), dim3(256), 0, stream,
                       wout_b, wv_b, pew, peb, pjwb, pjb, (float*)d_out);
}